// Round 7
// baseline (424.770 us; speedup 1.0000x reference)
//
#include <hip/hip_runtime.h>
#include <math.h>

// ---------------------------------------------------------------------------
// GCN diffusion forward on MI355X — round 7.
// vs R6:
//  * Aggregation inputs PRE-SCALED by dinv[row] (folded into producers):
//      out[dst] = dinv[dst] * (sum_{src} xs[src] + xs[dst]),  xs = x*dinv.
//    -> CSR payload is just src (4B): fill_csr write traffic halves.
//  * agg64: wave split into 4 quarters of 16 lanes; each quarter gathers a
//    different edge at 8B/lane (bf16x4) -> 4x memory-level parallelism.
//    Final cross-quarter reduce via 2 shfl_xor.
// Dataflow:
//   xt(bf16*dinv) -> agg0 -> aggX(bf16) -> G0[64->128,+b0,silu] -> h0(bf16)
//   h0 -> G1[128->64, *dinv] -> xw1(bf16) -> agg1(+b1,silu,*dinv) -> h1s(bf16)
//   h1s -> agg2 -> aggH1(bf16) -> G2[64->128,+b2,silu] -> h2(bf16)
//   (h2,h0) -> G3[cat 256->64, *dinv] -> z3(bf16) -> agg3(+b3,silu) -> out(f32)
// ---------------------------------------------------------------------------

typedef unsigned short ushortT;
typedef __attribute__((ext_vector_type(8))) short short8v;
typedef __attribute__((ext_vector_type(4))) float f32x4;

__device__ __forceinline__ ushortT f2bf(float f) {
    unsigned int u = __float_as_uint(f);
    u += 0x7FFFu + ((u >> 16) & 1u);     // round-to-nearest-even
    return (ushortT)(u >> 16);
}
__device__ __forceinline__ float bf2f(ushortT u) {
    return __uint_as_float(((unsigned int)u) << 16);
}
__device__ __forceinline__ void acc4(float4& a, uint2 v) {
    a.x += __uint_as_float(v.x << 16);
    a.y += __uint_as_float(v.x & 0xFFFF0000u);
    a.z += __uint_as_float(v.y << 16);
    a.w += __uint_as_float(v.y & 0xFFFF0000u);
}

__global__ __launch_bounds__(256) void zero_kernel(int* __restrict__ deg,
                                                   int* __restrict__ flag, int n) {
    int i = blockIdx.x * 256 + threadIdx.x;
    if (i < n) { deg[i] = 0; flag[i] = 0; }
}

__global__ __launch_bounds__(256) void count_deg_kernel(const int* __restrict__ ei,
                                                        int* __restrict__ deg, int e) {
    int i = blockIdx.x * 256 + threadIdx.x;
    if (i < e) atomicAdd(&deg[ei[e + i]], 1);   // dst row of edge_index
}

__global__ __launch_bounds__(256) void flags_kernel(const int* __restrict__ anm, int na,
                                                    const int* __restrict__ nrm, int nn,
                                                    int* __restrict__ flag) {
    int i = blockIdx.x * 256 + threadIdx.x;
    if (i < na) atomicMax(&flag[anm[i]], 1);
    if (i < nn) atomicMax(&flag[nrm[i]], 2);    // norm (2) overrides anm (1)
}

__global__ __launch_bounds__(256) void dinv_kernel(const int* __restrict__ deg,
                                                   float* __restrict__ dinv, int n) {
    int i = blockIdx.x * 256 + threadIdx.x;
    if (i < n) dinv[i] = rsqrtf((float)deg[i] + 1.0f);
}

// ---- exclusive scan of deg into rowstart (3-kernel, 1024 elems/block) ----
__global__ __launch_bounds__(256) void scan1_kernel(const int* __restrict__ deg,
                                                    int* __restrict__ rowstart,
                                                    int* __restrict__ blocksum, int n) {
    __shared__ int ts[256];
    int t = threadIdx.x;
    int base = blockIdx.x * 1024 + t * 4;
    int v0 = 0, v1 = 0, v2 = 0, v3 = 0;
    if (base + 0 < n) v0 = deg[base + 0];
    if (base + 1 < n) v1 = deg[base + 1];
    if (base + 2 < n) v2 = deg[base + 2];
    if (base + 3 < n) v3 = deg[base + 3];
    int s = v0 + v1 + v2 + v3;
    ts[t] = s;
    __syncthreads();
    for (int off = 1; off < 256; off <<= 1) {
        int add = (t >= off) ? ts[t - off] : 0;
        __syncthreads();
        ts[t] += add;
        __syncthreads();
    }
    if (t == 255) blocksum[blockIdx.x] = ts[255];
    int excl = ts[t] - s;
    if (base + 0 < n) rowstart[base + 0] = excl; excl += v0;
    if (base + 1 < n) rowstart[base + 1] = excl; excl += v1;
    if (base + 2 < n) rowstart[base + 2] = excl; excl += v2;
    if (base + 3 < n) rowstart[base + 3] = excl;
}

__global__ void scan2_kernel(int* __restrict__ blocksum, int nb) {
    if (threadIdx.x == 0 && blockIdx.x == 0) {
        int run = 0;
        for (int i = 0; i < nb; ++i) { int v = blocksum[i]; blocksum[i] = run; run += v; }
    }
}

__global__ __launch_bounds__(256) void scan3_kernel(int* __restrict__ rowstart,
                                                    const int* __restrict__ blocksum,
                                                    int* __restrict__ writepos, int n, int e) {
    int i = blockIdx.x * 256 + threadIdx.x;
    if (i < n) {
        int v = rowstart[i] + blocksum[i >> 10];
        rowstart[i] = v;
        writepos[i] = v;
    }
    if (i == 0) rowstart[n] = e;
}

// CSR fill: one 4B scattered write per edge (src index only)
__global__ __launch_bounds__(256) void fill_csr_kernel(const int* __restrict__ ei,
                                                       int* __restrict__ writepos,
                                                       int* __restrict__ cs, int e) {
    int i = blockIdx.x * 256 + threadIdx.x;
    if (i >= e) return;
    int src = ei[i];
    int dst = ei[e + i];
    int p = atomicAdd(&writepos[dst], 1);
    cs[p] = src;
}

// ---- time embedding MLP: [1,64] through two 64x64 layers with SiLU ----
__global__ void temb_kernel(const int* __restrict__ t,
                            const float* __restrict__ w1, const float* __restrict__ b1,
                            const float* __restrict__ w2, const float* __restrict__ b2,
                            float* __restrict__ temb) {
    __shared__ float emb[64], hid[64];
    int j = threadIdx.x;  // 64 threads
    float tf = (float)t[0];
    int h = j & 31;
    float freq = expf((float)h * -0.29710775393976190f);  // -ln(10000)/31
    float arg = tf * freq;
    emb[j] = (j < 32) ? sinf(arg) : cosf(arg);
    __syncthreads();
    float a = b1[j];
    for (int k = 0; k < 64; ++k) a = fmaf(emb[k], w1[k * 64 + j], a);
    hid[j] = a / (1.0f + expf(-a));  // SiLU
    __syncthreads();
    float o = b2[j];
    for (int k = 0; k < 64; ++k) o = fmaf(hid[k], w2[k * 64 + j], o);
    temb[j] = o;
}

// ---- x_t = (noise_x + temb + label_emb[flag]) * dinv[row]  -> bf16 ----
__global__ __launch_bounds__(256) void xt_kernel(const float* __restrict__ nx,
                                                 const float* __restrict__ temb,
                                                 const float* __restrict__ lemb,
                                                 const int* __restrict__ flag,
                                                 const float* __restrict__ dinv,
                                                 ushortT* __restrict__ xt, int n) {
    int t = blockIdx.x * 256 + threadIdx.x;
    int total = n * 16;
    if (t >= total) return;
    int row = t >> 4;
    int c4 = (t & 15) * 4;
    float4 v = *(const float4*)(nx + (size_t)row * 64 + c4);
    float4 tv = *(const float4*)(temb + c4);
    v.x += tv.x; v.y += tv.y; v.z += tv.z; v.w += tv.w;
    int f = flag[row];
    if (f) {
        const float* le = lemb + (f == 1 ? 64 : 0);  // 1->label_emb[1], 2->label_emb[0]
        float4 lv = *(const float4*)(le + c4);
        v.x += lv.x; v.y += lv.y; v.z += lv.z; v.w += lv.w;
    }
    float dv = dinv[row];
    v.x *= dv; v.y *= dv; v.z *= dv; v.w *= dv;
    unsigned int p0 = (unsigned int)f2bf(v.x) | ((unsigned int)f2bf(v.y) << 16);
    unsigned int p1 = (unsigned int)f2bf(v.z) | ((unsigned int)f2bf(v.w) << 16);
    *(uint2*)(xt + (size_t)row * 64 + c4) = make_uint2(p0, p1);
}

// ---- weight convert + swizzle to B-fragment order (all 4 gemms) ----
__global__ __launch_bounds__(256) void convw_kernel(const float* __restrict__ w0,
                                                    const float* __restrict__ w1,
                                                    const float* __restrict__ w2,
                                                    const float* __restrict__ w3,
                                                    ushortT* __restrict__ dst) {
    int i = blockIdx.x * 256 + threadIdx.x;
    if (i >= 40960) return;
    const float* src; int ST, M, base;
    if (i < 8192)       { src = w0; ST = 8; M = 128; base = 0; }
    else if (i < 16384) { src = w1; ST = 4; M = 64;  base = 8192; }
    else if (i < 24576) { src = w2; ST = 8; M = 128; base = 16384; }
    else                { src = w3; ST = 4; M = 64;  base = 24576; }
    int idx = i - base;
    int j = idx & 7;
    int lane = (idx >> 3) & 63;
    int rest = idx >> 9;
    int s = rest % ST;
    int kq = rest / ST;
    int k = kq * 32 + (lane >> 4) * 8 + j;
    int col = s * 16 + (lane & 15);
    dst[i] = f2bf(src[(size_t)k * M + col]);
}

// ---------------------------------------------------------------------------
// MFMA GEMM: Y[n][M] = A[n][K] @ W (bf16 in, f32 acc). Wave = 16 rows x M.
// Block = 4 waves = 64 rows. No LDS. SCALE: multiply output row by dinv[row].
// ---------------------------------------------------------------------------
template <int KQT, int ST, bool BIAS_SILU, bool OUT_BF16, bool CAT, bool SCALE>
__global__ __launch_bounds__(256) void mfma_gemm_kernel(const ushortT* __restrict__ A1,
                                                        const ushortT* __restrict__ A2,
                                                        const ushortT* __restrict__ Wswz,
                                                        const float* __restrict__ bias,
                                                        const float* __restrict__ dinvp,
                                                        void* __restrict__ Yv, int n) {
    constexpr int M = ST * 16;
    constexpr int KA = (CAT ? (KQT / 2) : KQT) * 32;   // per-source row stride
    const int lane = threadIdx.x & 63;
    const int wid = threadIdx.x >> 6;
    const int row0 = blockIdx.x * 64 + wid * 16;
    const int arow = row0 + (lane & 15);
    const int kb = (lane >> 4) * 8;

    f32x4 acc[ST];
#pragma unroll
    for (int s = 0; s < ST; ++s) acc[s] = (f32x4){0.f, 0.f, 0.f, 0.f};

#pragma unroll
    for (int kq = 0; kq < KQT; ++kq) {
        const ushortT* Asrc = (CAT && kq >= KQT / 2) ? A2 : A1;
        const int kloc = (CAT && kq >= KQT / 2) ? (kq - KQT / 2) * 32 : kq * 32;
        short8v a = *(const short8v*)(Asrc + (size_t)arow * KA + kloc + kb);
        const ushortT* wp = Wswz + ((size_t)(kq * ST) * 64 + lane) * 8;
#pragma unroll
        for (int s = 0; s < ST; ++s) {
            short8v b = *(const short8v*)(wp + (size_t)s * 64 * 8);
            acc[s] = __builtin_amdgcn_mfma_f32_16x16x32_bf16(a, b, acc[s], 0, 0, 0);
        }
    }

    const int dcol = lane & 15;
    const int drow0 = row0 + (lane >> 4) * 4;
    float sc[4];
    if (SCALE) {
#pragma unroll
        for (int r = 0; r < 4; ++r) sc[r] = (drow0 + r < n) ? dinvp[drow0 + r] : 0.f;
    }
#pragma unroll
    for (int s = 0; s < ST; ++s) {
        float bv = BIAS_SILU ? bias[s * 16 + dcol] : 0.f;
#pragma unroll
        for (int r = 0; r < 4; ++r) {
            int row = drow0 + r;
            if (row >= n) continue;
            float v = acc[s][r];
            if (BIAS_SILU) { v += bv; v = v / (1.0f + expf(-v)); }
            if (SCALE) v *= sc[r];
            if (OUT_BF16) ((ushortT*)Yv)[(size_t)row * M + s * 16 + dcol] = f2bf(v);
            else          ((float*)Yv)[(size_t)row * M + s * 16 + dcol] = v;
        }
    }
}

// ---------------------------------------------------------------------------
// agg over 64-dim pre-scaled bf16 rows. One wave per node; 4 quarters of 16
// lanes each gather a DIFFERENT edge at 8B/lane (bf16x4) -> 4x MLP.
// out[dst] = dinv[dst] * (sum_src xs[src] + xs[dst])  (+bias,silu,post-scale)
// ---------------------------------------------------------------------------
template <bool BIAS_SILU, bool OUT_BF16, bool POST_SCALE>
__global__ __launch_bounds__(256) void agg64_kernel(const ushortT* __restrict__ xw,
                                                    const int* __restrict__ rowstart,
                                                    const int* __restrict__ cs,
                                                    const float* __restrict__ dinv,
                                                    const float* __restrict__ bias,
                                                    void* __restrict__ yv, int n) {
    int wv = (int)(((size_t)blockIdx.x * 256 + threadIdx.x) >> 6);
    int lane = threadIdx.x & 63;
    if (wv >= n) return;
    int q = lane >> 4;        // quarter: which edge of a group of 4
    int sl = lane & 15;       // sub-lane: dims sl*4 .. sl*4+3
    int s = rowstart[wv], e1 = rowstart[wv + 1];
    float4 acc = make_float4(0.f, 0.f, 0.f, 0.f);
    int e = s;
    for (; e + 16 <= e1; e += 16) {
        int c0 = cs[e + q];
        int c1 = cs[e + 4 + q];
        int c2 = cs[e + 8 + q];
        int c3 = cs[e + 12 + q];
        uint2 v0 = *((const uint2*)(xw + (size_t)c0 * 64) + sl);
        uint2 v1 = *((const uint2*)(xw + (size_t)c1 * 64) + sl);
        uint2 v2 = *((const uint2*)(xw + (size_t)c2 * 64) + sl);
        uint2 v3 = *((const uint2*)(xw + (size_t)c3 * 64) + sl);
        acc4(acc, v0); acc4(acc, v1); acc4(acc, v2); acc4(acc, v3);
    }
    for (; e < e1; e += 4) {
        int idx = e + q;
        if (idx < e1) {
            int c = cs[idx];
            uint2 v = *((const uint2*)(xw + (size_t)c * 64) + sl);
            acc4(acc, v);
        }
    }
    // cross-quarter reduce (quarters hold disjoint edge subsets of same dims)
    acc.x += __shfl_xor(acc.x, 16); acc.y += __shfl_xor(acc.y, 16);
    acc.z += __shfl_xor(acc.z, 16); acc.w += __shfl_xor(acc.w, 16);
    acc.x += __shfl_xor(acc.x, 32); acc.y += __shfl_xor(acc.y, 32);
    acc.z += __shfl_xor(acc.z, 32); acc.w += __shfl_xor(acc.w, 32);
    if (q == 0) {
        float di = dinv[wv];
        uint2 sv = *((const uint2*)(xw + (size_t)wv * 64) + sl);
        acc4(acc, sv);                       // self term (pre-scaled row)
        acc.x *= di; acc.y *= di; acc.z *= di; acc.w *= di;
        if (BIAS_SILU) {
            float4 b = *(const float4*)(bias + sl * 4);
            acc.x += b.x; acc.y += b.y; acc.z += b.z; acc.w += b.w;
            acc.x = acc.x / (1.0f + expf(-acc.x));
            acc.y = acc.y / (1.0f + expf(-acc.y));
            acc.z = acc.z / (1.0f + expf(-acc.z));
            acc.w = acc.w / (1.0f + expf(-acc.w));
        }
        if (POST_SCALE) { acc.x *= di; acc.y *= di; acc.z *= di; acc.w *= di; }
        if (OUT_BF16) {
            uint2 r;
            r.x = (unsigned int)f2bf(acc.x) | ((unsigned int)f2bf(acc.y) << 16);
            r.y = (unsigned int)f2bf(acc.z) | ((unsigned int)f2bf(acc.w) << 16);
            *((uint2*)yv + (size_t)wv * 16 + sl) = r;
        } else {
            *((float4*)yv + (size_t)wv * 16 + sl) = acc;
        }
    }
}

extern "C" void kernel_launch(void* const* d_in, const int* in_sizes, int n_in,
                              void* d_out, int out_size, void* d_ws, size_t ws_size,
                              hipStream_t stream) {
    const float* noise_x = (const float*)d_in[0];
    const int*   edge    = (const int*)d_in[1];
    const int*   tptr    = (const int*)d_in[2];
    const int*   anm     = (const int*)d_in[3];
    const int*   nrm     = (const int*)d_in[4];
    const float* tw1     = (const float*)d_in[5];
    const float* tb1     = (const float*)d_in[6];
    const float* tw2     = (const float*)d_in[7];
    const float* tb2     = (const float*)d_in[8];
    const float* lemb    = (const float*)d_in[9];
    const float* w0      = (const float*)d_in[10];
    const float* b0      = (const float*)d_in[11];
    const float* w1      = (const float*)d_in[12];
    const float* b1      = (const float*)d_in[13];
    const float* w2      = (const float*)d_in[14];
    const float* b2      = (const float*)d_in[15];
    const float* w3      = (const float*)d_in[16];
    const float* b3      = (const float*)d_in[17];

    const int N = in_sizes[0] / 64;
    const int E = in_sizes[1] / 2;
    const int na = in_sizes[3];
    const int nn = in_sizes[4];
    float* out = (float*)d_out;

    // workspace carve-out (256B aligned)
    char* ws = (char*)d_ws;
    size_t o = 0;
    auto carve = [&](size_t bytes) -> char* {
        char* p = ws + o;
        o += (bytes + 255) & ~(size_t)255;
        return p;
    };
    int*     deg      = (int*)carve((size_t)N * 4);
    int*     flag     = (int*)carve((size_t)N * 4);
    int*     rowstart = (int*)carve((size_t)(N + 1) * 4);
    int*     writepos = (int*)carve((size_t)N * 4);
    int*     blocksum = (int*)carve(4096);
    int*     cs       = (int*)carve((size_t)E * 4);
    float*   dinv     = (float*)carve((size_t)N * 4);
    float*   temb     = (float*)carve(256);
    ushortT* wswz     = (ushortT*)carve(40960 * 2);
    ushortT* bufXT    = (ushortT*)carve((size_t)N * 64 * 2);  // x_t*dinv, reused as h1s
    ushortT* aggX     = (ushortT*)carve((size_t)N * 64 * 2);  // agg0 out (bf16)
    ushortT* h0       = (ushortT*)carve((size_t)N * 128 * 2); // G0 out (bf16)
    ushortT* xw1      = (ushortT*)carve((size_t)N * 64 * 2);  // G1 out *dinv, reused as z3
    ushortT* aggH1    = (ushortT*)carve((size_t)N * 64 * 2);  // agg2 out (bf16)
    ushortT* h2       = (ushortT*)carve((size_t)N * 128 * 2); // G2 out (bf16)
    ushortT* h1s      = bufXT;                                 // reuse
    ushortT* z3       = xw1;                                   // reuse

    const int nblkN = (N + 255) / 256;
    const int nblkE = (E + 255) / 256;
    const int nb = (N + 1023) / 1024;
    const int nmax = na > nn ? na : nn;
    const int aggBlk = (N + 3) / 4;          // 4 waves (nodes) per 256-thread block
    const int gblk = (N + 63) / 64;          // 64 rows per mfma-gemm block

    zero_kernel<<<nblkN, 256, 0, stream>>>(deg, flag, N);
    count_deg_kernel<<<nblkE, 256, 0, stream>>>(edge, deg, E);
    flags_kernel<<<(nmax + 255) / 256, 256, 0, stream>>>(anm, na, nrm, nn, flag);
    dinv_kernel<<<nblkN, 256, 0, stream>>>(deg, dinv, N);
    scan1_kernel<<<nb, 256, 0, stream>>>(deg, rowstart, blocksum, N);
    scan2_kernel<<<1, 64, 0, stream>>>(blocksum, nb);
    scan3_kernel<<<nblkN, 256, 0, stream>>>(rowstart, blocksum, writepos, N, E);
    fill_csr_kernel<<<nblkE, 256, 0, stream>>>(edge, writepos, cs, E);
    convw_kernel<<<160, 256, 0, stream>>>(w0, w1, w2, w3, wswz);
    temb_kernel<<<1, 64, 0, stream>>>(tptr, tw1, tb1, tw2, tb2, temb);
    xt_kernel<<<((size_t)N * 16 + 255) / 256, 256, 0, stream>>>(noise_x, temb, lemb, flag, dinv, bufXT, N);

    // conv0: aggX = agg(x_t) [bf16]; h0 = silu(aggX @ w0 + b0) [bf16]
    agg64_kernel<false, true, false><<<aggBlk, 256, 0, stream>>>(bufXT, rowstart, cs, dinv, nullptr, aggX, N);
    mfma_gemm_kernel<2, 8, true, true, false, false><<<gblk, 256, 0, stream>>>(aggX, nullptr, wswz, b0, nullptr, h0, N);
    // conv1: xw1 = (h0 @ w1)*dinv [bf16]; h1s = silu(agg+b1)*dinv [bf16]
    mfma_gemm_kernel<4, 4, false, true, false, true><<<gblk, 256, 0, stream>>>(h0, nullptr, wswz + 8192, nullptr, dinv, xw1, N);
    agg64_kernel<true, true, true><<<aggBlk, 256, 0, stream>>>(xw1, rowstart, cs, dinv, b1, h1s, N);
    // conv2: aggH1 = agg(h1) [bf16]; h2 = silu(aggH1 @ w2 + b2) [bf16]
    agg64_kernel<false, true, false><<<aggBlk, 256, 0, stream>>>(h1s, rowstart, cs, dinv, nullptr, aggH1, N);
    mfma_gemm_kernel<2, 8, true, true, false, false><<<gblk, 256, 0, stream>>>(aggH1, nullptr, wswz + 16384, b2, nullptr, h2, N);
    // conv3: z3 = (h2 @ w3a + h0 @ w3b)*dinv [bf16]; out = silu(agg + b3) [f32]
    mfma_gemm_kernel<8, 4, false, true, true, true><<<gblk, 256, 0, stream>>>(h2, h0, wswz + 24576, nullptr, dinv, z3, N);
    agg64_kernel<true, false, false><<<aggBlk, 256, 0, stream>>>(z3, rowstart, cs, dinv, b3, out, N);
}

// Round 8
// 383.173 us; speedup vs baseline: 1.1086x; 1.1086x over previous
//
#include <hip/hip_runtime.h>
#include <math.h>

// ---------------------------------------------------------------------------
// GCN diffusion forward on MI355X — round 8.
// vs R7:
//  * fill_csr XCD-partitioned: 8x blocks; block (blockIdx&7) only handles
//    edges with dst-bucket == blockIdx&7 (bucket = dst / ceil(N/8)). With the
//    de-facto round-robin blockIdx->XCD mapping, each cs line is dirtied by
//    ONE XCD's L2 -> writeback amplification 17x -> ~1x. (Correctness does
//    not depend on the mapping.)
//  * agg64 reverted to R6 structure (full-row 2B/lane, unroll x8) but with
//    pre-scaled rows (R7) and 4B cs indices: per-edge ADD, no weight.
// Dataflow:
//   xt(bf16*dinv) -> agg0 -> aggX(bf16) -> G0[64->128,+b0,silu] -> h0(bf16)
//   h0 -> G1[128->64, *dinv] -> xw1(bf16) -> agg1(+b1,silu,*dinv) -> h1s(bf16)
//   h1s -> agg2 -> aggH1(bf16) -> G2[64->128,+b2,silu] -> h2(bf16)
//   (h2,h0) -> G3[cat 256->64, *dinv] -> z3(bf16) -> agg3(+b3,silu) -> out(f32)
// ---------------------------------------------------------------------------

typedef unsigned short ushortT;
typedef __attribute__((ext_vector_type(8))) short short8v;
typedef __attribute__((ext_vector_type(4))) float f32x4;

__device__ __forceinline__ ushortT f2bf(float f) {
    unsigned int u = __float_as_uint(f);
    u += 0x7FFFu + ((u >> 16) & 1u);     // round-to-nearest-even
    return (ushortT)(u >> 16);
}
__device__ __forceinline__ float bf2f(ushortT u) {
    return __uint_as_float(((unsigned int)u) << 16);
}

__global__ __launch_bounds__(256) void zero_kernel(int* __restrict__ deg,
                                                   int* __restrict__ flag, int n) {
    int i = blockIdx.x * 256 + threadIdx.x;
    if (i < n) { deg[i] = 0; flag[i] = 0; }
}

__global__ __launch_bounds__(256) void count_deg_kernel(const int* __restrict__ ei,
                                                        int* __restrict__ deg, int e) {
    int i = blockIdx.x * 256 + threadIdx.x;
    if (i < e) atomicAdd(&deg[ei[e + i]], 1);   // dst row of edge_index
}

__global__ __launch_bounds__(256) void flags_kernel(const int* __restrict__ anm, int na,
                                                    const int* __restrict__ nrm, int nn,
                                                    int* __restrict__ flag) {
    int i = blockIdx.x * 256 + threadIdx.x;
    if (i < na) atomicMax(&flag[anm[i]], 1);
    if (i < nn) atomicMax(&flag[nrm[i]], 2);    // norm (2) overrides anm (1)
}

__global__ __launch_bounds__(256) void dinv_kernel(const int* __restrict__ deg,
                                                   float* __restrict__ dinv, int n) {
    int i = blockIdx.x * 256 + threadIdx.x;
    if (i < n) dinv[i] = rsqrtf((float)deg[i] + 1.0f);
}

// ---- exclusive scan of deg into rowstart (3-kernel, 1024 elems/block) ----
__global__ __launch_bounds__(256) void scan1_kernel(const int* __restrict__ deg,
                                                    int* __restrict__ rowstart,
                                                    int* __restrict__ blocksum, int n) {
    __shared__ int ts[256];
    int t = threadIdx.x;
    int base = blockIdx.x * 1024 + t * 4;
    int v0 = 0, v1 = 0, v2 = 0, v3 = 0;
    if (base + 0 < n) v0 = deg[base + 0];
    if (base + 1 < n) v1 = deg[base + 1];
    if (base + 2 < n) v2 = deg[base + 2];
    if (base + 3 < n) v3 = deg[base + 3];
    int s = v0 + v1 + v2 + v3;
    ts[t] = s;
    __syncthreads();
    for (int off = 1; off < 256; off <<= 1) {
        int add = (t >= off) ? ts[t - off] : 0;
        __syncthreads();
        ts[t] += add;
        __syncthreads();
    }
    if (t == 255) blocksum[blockIdx.x] = ts[255];
    int excl = ts[t] - s;
    if (base + 0 < n) rowstart[base + 0] = excl; excl += v0;
    if (base + 1 < n) rowstart[base + 1] = excl; excl += v1;
    if (base + 2 < n) rowstart[base + 2] = excl; excl += v2;
    if (base + 3 < n) rowstart[base + 3] = excl;
}

__global__ void scan2_kernel(int* __restrict__ blocksum, int nb) {
    if (threadIdx.x == 0 && blockIdx.x == 0) {
        int run = 0;
        for (int i = 0; i < nb; ++i) { int v = blocksum[i]; blocksum[i] = run; run += v; }
    }
}

__global__ __launch_bounds__(256) void scan3_kernel(int* __restrict__ rowstart,
                                                    const int* __restrict__ blocksum,
                                                    int* __restrict__ writepos, int n, int e) {
    int i = blockIdx.x * 256 + threadIdx.x;
    if (i < n) {
        int v = rowstart[i] + blocksum[i >> 10];
        rowstart[i] = v;
        writepos[i] = v;
    }
    if (i == 0) rowstart[n] = e;
}

// CSR fill, XCD-partitioned: block handles edge chunk (blockIdx>>3); only
// edges whose dst bucket == (blockIdx&7) are written by this block.
__global__ __launch_bounds__(256) void fill_csr_kernel(const int* __restrict__ ei,
                                                       int* __restrict__ writepos,
                                                       int* __restrict__ cs, int e, int bdiv) {
    int xcd = blockIdx.x & 7;
    int i = (blockIdx.x >> 3) * 256 + threadIdx.x;
    if (i >= e) return;
    int dst = ei[e + i];
    if (dst / bdiv != xcd) return;
    int src = ei[i];
    int p = atomicAdd(&writepos[dst], 1);
    cs[p] = src;
}

// ---- time embedding MLP: [1,64] through two 64x64 layers with SiLU ----
__global__ void temb_kernel(const int* __restrict__ t,
                            const float* __restrict__ w1, const float* __restrict__ b1,
                            const float* __restrict__ w2, const float* __restrict__ b2,
                            float* __restrict__ temb) {
    __shared__ float emb[64], hid[64];
    int j = threadIdx.x;  // 64 threads
    float tf = (float)t[0];
    int h = j & 31;
    float freq = expf((float)h * -0.29710775393976190f);  // -ln(10000)/31
    float arg = tf * freq;
    emb[j] = (j < 32) ? sinf(arg) : cosf(arg);
    __syncthreads();
    float a = b1[j];
    for (int k = 0; k < 64; ++k) a = fmaf(emb[k], w1[k * 64 + j], a);
    hid[j] = a / (1.0f + expf(-a));  // SiLU
    __syncthreads();
    float o = b2[j];
    for (int k = 0; k < 64; ++k) o = fmaf(hid[k], w2[k * 64 + j], o);
    temb[j] = o;
}

// ---- x_t = (noise_x + temb + label_emb[flag]) * dinv[row]  -> bf16 ----
__global__ __launch_bounds__(256) void xt_kernel(const float* __restrict__ nx,
                                                 const float* __restrict__ temb,
                                                 const float* __restrict__ lemb,
                                                 const int* __restrict__ flag,
                                                 const float* __restrict__ dinv,
                                                 ushortT* __restrict__ xt, int n) {
    int t = blockIdx.x * 256 + threadIdx.x;
    int total = n * 16;
    if (t >= total) return;
    int row = t >> 4;
    int c4 = (t & 15) * 4;
    float4 v = *(const float4*)(nx + (size_t)row * 64 + c4);
    float4 tv = *(const float4*)(temb + c4);
    v.x += tv.x; v.y += tv.y; v.z += tv.z; v.w += tv.w;
    int f = flag[row];
    if (f) {
        const float* le = lemb + (f == 1 ? 64 : 0);  // 1->label_emb[1], 2->label_emb[0]
        float4 lv = *(const float4*)(le + c4);
        v.x += lv.x; v.y += lv.y; v.z += lv.z; v.w += lv.w;
    }
    float dv = dinv[row];
    v.x *= dv; v.y *= dv; v.z *= dv; v.w *= dv;
    unsigned int p0 = (unsigned int)f2bf(v.x) | ((unsigned int)f2bf(v.y) << 16);
    unsigned int p1 = (unsigned int)f2bf(v.z) | ((unsigned int)f2bf(v.w) << 16);
    *(uint2*)(xt + (size_t)row * 64 + c4) = make_uint2(p0, p1);
}

// ---- weight convert + swizzle to B-fragment order (all 4 gemms) ----
__global__ __launch_bounds__(256) void convw_kernel(const float* __restrict__ w0,
                                                    const float* __restrict__ w1,
                                                    const float* __restrict__ w2,
                                                    const float* __restrict__ w3,
                                                    ushortT* __restrict__ dst) {
    int i = blockIdx.x * 256 + threadIdx.x;
    if (i >= 40960) return;
    const float* src; int ST, M, base;
    if (i < 8192)       { src = w0; ST = 8; M = 128; base = 0; }
    else if (i < 16384) { src = w1; ST = 4; M = 64;  base = 8192; }
    else if (i < 24576) { src = w2; ST = 8; M = 128; base = 16384; }
    else                { src = w3; ST = 4; M = 64;  base = 24576; }
    int idx = i - base;
    int j = idx & 7;
    int lane = (idx >> 3) & 63;
    int rest = idx >> 9;
    int s = rest % ST;
    int kq = rest / ST;
    int k = kq * 32 + (lane >> 4) * 8 + j;
    int col = s * 16 + (lane & 15);
    dst[i] = f2bf(src[(size_t)k * M + col]);
}

// ---------------------------------------------------------------------------
// MFMA GEMM: Y[n][M] = A[n][K] @ W (bf16 in, f32 acc). Wave = 16 rows x M.
// Block = 4 waves = 64 rows. No LDS. SCALE: multiply output row by dinv[row].
// ---------------------------------------------------------------------------
template <int KQT, int ST, bool BIAS_SILU, bool OUT_BF16, bool CAT, bool SCALE>
__global__ __launch_bounds__(256) void mfma_gemm_kernel(const ushortT* __restrict__ A1,
                                                        const ushortT* __restrict__ A2,
                                                        const ushortT* __restrict__ Wswz,
                                                        const float* __restrict__ bias,
                                                        const float* __restrict__ dinvp,
                                                        void* __restrict__ Yv, int n) {
    constexpr int M = ST * 16;
    constexpr int KA = (CAT ? (KQT / 2) : KQT) * 32;   // per-source row stride
    const int lane = threadIdx.x & 63;
    const int wid = threadIdx.x >> 6;
    const int row0 = blockIdx.x * 64 + wid * 16;
    const int arow = row0 + (lane & 15);
    const int kb = (lane >> 4) * 8;

    f32x4 acc[ST];
#pragma unroll
    for (int s = 0; s < ST; ++s) acc[s] = (f32x4){0.f, 0.f, 0.f, 0.f};

#pragma unroll
    for (int kq = 0; kq < KQT; ++kq) {
        const ushortT* Asrc = (CAT && kq >= KQT / 2) ? A2 : A1;
        const int kloc = (CAT && kq >= KQT / 2) ? (kq - KQT / 2) * 32 : kq * 32;
        short8v a = *(const short8v*)(Asrc + (size_t)arow * KA + kloc + kb);
        const ushortT* wp = Wswz + ((size_t)(kq * ST) * 64 + lane) * 8;
#pragma unroll
        for (int s = 0; s < ST; ++s) {
            short8v b = *(const short8v*)(wp + (size_t)s * 64 * 8);
            acc[s] = __builtin_amdgcn_mfma_f32_16x16x32_bf16(a, b, acc[s], 0, 0, 0);
        }
    }

    const int dcol = lane & 15;
    const int drow0 = row0 + (lane >> 4) * 4;
    float sc[4];
    if (SCALE) {
#pragma unroll
        for (int r = 0; r < 4; ++r) sc[r] = (drow0 + r < n) ? dinvp[drow0 + r] : 0.f;
    }
#pragma unroll
    for (int s = 0; s < ST; ++s) {
        float bv = BIAS_SILU ? bias[s * 16 + dcol] : 0.f;
#pragma unroll
        for (int r = 0; r < 4; ++r) {
            int row = drow0 + r;
            if (row >= n) continue;
            float v = acc[s][r];
            if (BIAS_SILU) { v += bv; v = v / (1.0f + expf(-v)); }
            if (SCALE) v *= sc[r];
            if (OUT_BF16) ((ushortT*)Yv)[(size_t)row * M + s * 16 + dcol] = f2bf(v);
            else          ((float*)Yv)[(size_t)row * M + s * 16 + dcol] = v;
        }
    }
}

// ---------------------------------------------------------------------------
// agg over 64-dim PRE-SCALED bf16 rows: one wave per node, full row (2B/lane),
// unroll x8. out[dst] = dinv[dst]*(sum_src xs[src] + xs[dst]) (+bias,silu).
// ---------------------------------------------------------------------------
template <bool BIAS_SILU, bool OUT_BF16, bool POST_SCALE>
__global__ __launch_bounds__(256) void agg64_kernel(const ushortT* __restrict__ xw,
                                                    const int* __restrict__ rowstart,
                                                    const int* __restrict__ cs,
                                                    const float* __restrict__ dinv,
                                                    const float* __restrict__ bias,
                                                    void* __restrict__ yv, int n) {
    int wv = (int)(((size_t)blockIdx.x * 256 + threadIdx.x) >> 6);
    int lane = threadIdx.x & 63;
    if (wv >= n) return;
    float di = dinv[wv];
    int s = rowstart[wv], e1 = rowstart[wv + 1];
    float a0 = 0.f, a1 = 0.f, a2 = 0.f, a3 = 0.f;
    float a4 = 0.f, a5 = 0.f, a6 = 0.f, a7 = 0.f;
    int e = s;
    for (; e + 8 <= e1; e += 8) {
        int c0 = cs[e],     c1 = cs[e + 1], c2 = cs[e + 2], c3 = cs[e + 3];
        int c4 = cs[e + 4], c5 = cs[e + 5], c6 = cs[e + 6], c7 = cs[e + 7];
        a0 += bf2f(xw[(size_t)c0 * 64 + lane]);
        a1 += bf2f(xw[(size_t)c1 * 64 + lane]);
        a2 += bf2f(xw[(size_t)c2 * 64 + lane]);
        a3 += bf2f(xw[(size_t)c3 * 64 + lane]);
        a4 += bf2f(xw[(size_t)c4 * 64 + lane]);
        a5 += bf2f(xw[(size_t)c5 * 64 + lane]);
        a6 += bf2f(xw[(size_t)c6 * 64 + lane]);
        a7 += bf2f(xw[(size_t)c7 * 64 + lane]);
    }
    for (; e + 4 <= e1; e += 4) {
        int c0 = cs[e], c1 = cs[e + 1], c2 = cs[e + 2], c3 = cs[e + 3];
        a0 += bf2f(xw[(size_t)c0 * 64 + lane]);
        a1 += bf2f(xw[(size_t)c1 * 64 + lane]);
        a2 += bf2f(xw[(size_t)c2 * 64 + lane]);
        a3 += bf2f(xw[(size_t)c3 * 64 + lane]);
    }
    for (; e < e1; ++e) {
        a0 += bf2f(xw[(size_t)cs[e] * 64 + lane]);
    }
    float acc = ((a0 + a1) + (a2 + a3)) + ((a4 + a5) + (a6 + a7));
    acc += bf2f(xw[(size_t)wv * 64 + lane]);   // self term (pre-scaled row)
    acc *= di;
    if (BIAS_SILU) {
        acc += bias[lane];
        acc = acc / (1.0f + expf(-acc));
    }
    if (POST_SCALE) acc *= di;
    if (OUT_BF16) ((ushortT*)yv)[(size_t)wv * 64 + lane] = f2bf(acc);
    else          ((float*)yv)[(size_t)wv * 64 + lane] = acc;
}

extern "C" void kernel_launch(void* const* d_in, const int* in_sizes, int n_in,
                              void* d_out, int out_size, void* d_ws, size_t ws_size,
                              hipStream_t stream) {
    const float* noise_x = (const float*)d_in[0];
    const int*   edge    = (const int*)d_in[1];
    const int*   tptr    = (const int*)d_in[2];
    const int*   anm     = (const int*)d_in[3];
    const int*   nrm     = (const int*)d_in[4];
    const float* tw1     = (const float*)d_in[5];
    const float* tb1     = (const float*)d_in[6];
    const float* tw2     = (const float*)d_in[7];
    const float* tb2     = (const float*)d_in[8];
    const float* lemb    = (const float*)d_in[9];
    const float* w0      = (const float*)d_in[10];
    const float* b0      = (const float*)d_in[11];
    const float* w1      = (const float*)d_in[12];
    const float* b1      = (const float*)d_in[13];
    const float* w2      = (const float*)d_in[14];
    const float* b2      = (const float*)d_in[15];
    const float* w3      = (const float*)d_in[16];
    const float* b3      = (const float*)d_in[17];

    const int N = in_sizes[0] / 64;
    const int E = in_sizes[1] / 2;
    const int na = in_sizes[3];
    const int nn = in_sizes[4];
    float* out = (float*)d_out;

    // workspace carve-out (256B aligned)
    char* ws = (char*)d_ws;
    size_t o = 0;
    auto carve = [&](size_t bytes) -> char* {
        char* p = ws + o;
        o += (bytes + 255) & ~(size_t)255;
        return p;
    };
    int*     deg      = (int*)carve((size_t)N * 4);
    int*     flag     = (int*)carve((size_t)N * 4);
    int*     rowstart = (int*)carve((size_t)(N + 1) * 4);
    int*     writepos = (int*)carve((size_t)N * 4);
    int*     blocksum = (int*)carve(4096);
    int*     cs       = (int*)carve((size_t)E * 4);
    float*   dinv     = (float*)carve((size_t)N * 4);
    float*   temb     = (float*)carve(256);
    ushortT* wswz     = (ushortT*)carve(40960 * 2);
    ushortT* bufXT    = (ushortT*)carve((size_t)N * 64 * 2);  // x_t*dinv, reused as h1s
    ushortT* aggX     = (ushortT*)carve((size_t)N * 64 * 2);  // agg0 out (bf16)
    ushortT* h0       = (ushortT*)carve((size_t)N * 128 * 2); // G0 out (bf16)
    ushortT* xw1      = (ushortT*)carve((size_t)N * 64 * 2);  // G1 out *dinv, reused as z3
    ushortT* aggH1    = (ushortT*)carve((size_t)N * 64 * 2);  // agg2 out (bf16)
    ushortT* h2       = (ushortT*)carve((size_t)N * 128 * 2); // G2 out (bf16)
    ushortT* h1s      = bufXT;                                 // reuse
    ushortT* z3       = xw1;                                   // reuse

    const int nblkN = (N + 255) / 256;
    const int nblkE = (E + 255) / 256;
    const int nb = (N + 1023) / 1024;
    const int nmax = na > nn ? na : nn;
    const int aggBlk = (N + 3) / 4;          // 4 waves (nodes) per 256-thread block
    const int gblk = (N + 63) / 64;          // 64 rows per mfma-gemm block
    const int bdiv = (N + 7) / 8;            // dst bucket size for XCD partition

    zero_kernel<<<nblkN, 256, 0, stream>>>(deg, flag, N);
    count_deg_kernel<<<nblkE, 256, 0, stream>>>(edge, deg, E);
    flags_kernel<<<(nmax + 255) / 256, 256, 0, stream>>>(anm, na, nrm, nn, flag);
    dinv_kernel<<<nblkN, 256, 0, stream>>>(deg, dinv, N);
    scan1_kernel<<<nb, 256, 0, stream>>>(deg, rowstart, blocksum, N);
    scan2_kernel<<<1, 64, 0, stream>>>(blocksum, nb);
    scan3_kernel<<<nblkN, 256, 0, stream>>>(rowstart, blocksum, writepos, N, E);
    fill_csr_kernel<<<8 * nblkE, 256, 0, stream>>>(edge, writepos, cs, E, bdiv);
    convw_kernel<<<160, 256, 0, stream>>>(w0, w1, w2, w3, wswz);
    temb_kernel<<<1, 64, 0, stream>>>(tptr, tw1, tb1, tw2, tb2, temb);
    xt_kernel<<<((size_t)N * 16 + 255) / 256, 256, 0, stream>>>(noise_x, temb, lemb, flag, dinv, bufXT, N);

    // conv0: aggX = agg(x_t) [bf16]; h0 = silu(aggX @ w0 + b0) [bf16]
    agg64_kernel<false, true, false><<<aggBlk, 256, 0, stream>>>(bufXT, rowstart, cs, dinv, nullptr, aggX, N);
    mfma_gemm_kernel<2, 8, true, true, false, false><<<gblk, 256, 0, stream>>>(aggX, nullptr, wswz, b0, nullptr, h0, N);
    // conv1: xw1 = (h0 @ w1)*dinv [bf16]; h1s = silu(agg+b1)*dinv [bf16]
    mfma_gemm_kernel<4, 4, false, true, false, true><<<gblk, 256, 0, stream>>>(h0, nullptr, wswz + 8192, nullptr, dinv, xw1, N);
    agg64_kernel<true, true, true><<<aggBlk, 256, 0, stream>>>(xw1, rowstart, cs, dinv, b1, h1s, N);
    // conv2: aggH1 = agg(h1) [bf16]; h2 = silu(aggH1 @ w2 + b2) [bf16]
    agg64_kernel<false, true, false><<<aggBlk, 256, 0, stream>>>(h1s, rowstart, cs, dinv, nullptr, aggH1, N);
    mfma_gemm_kernel<2, 8, true, true, false, false><<<gblk, 256, 0, stream>>>(aggH1, nullptr, wswz + 16384, b2, nullptr, h2, N);
    // conv3: z3 = (h2 @ w3a + h0 @ w3b)*dinv [bf16]; out = silu(agg + b3) [f32]
    mfma_gemm_kernel<8, 4, false, true, true, true><<<gblk, 256, 0, stream>>>(h2, h0, wswz + 24576, nullptr, dinv, z3, N);
    agg64_kernel<true, false, false><<<aggBlk, 256, 0, stream>>>(z3, rowstart, cs, dinv, b3, out, N);
}